// Round 4
// baseline (718.573 us; speedup 1.0000x reference)
//
#include <hip/hip_runtime.h>
#include <math.h>

#define N_NODES   20000
#define N_PAD     20032   // 626 * 32
#define N_EDGES   320000
#define N_GRAPHS  64
#define IN_FEAT   64
#define HIDDEN    256
#define GRID_F    4
#define NLAYERS   3
#define NEG_SLOPE 0.01f

#define KF 2048   // fourier K = HIDDEN * 8 (cos/sin x k=1..4)
#define KL 320    // line K = IN_FEAT * 5 (degrees 0..4)
#define NB_SCAN 79  // ceil(20000/256)

typedef _Float16 f16x8 __attribute__((ext_vector_type(8)));
typedef float    f32x4 __attribute__((ext_vector_type(4)));

// ---------- weight transposes ----------
// fp16 Bt[l][o][kk], kk = i*8 + t*4 + g  (t=0:cos,1:sin ; g -> harmonic k=g+1)
__global__ void transpose_fourier_f16(const float* __restrict__ fc, _Float16* __restrict__ Bt) {
    int idx = blockIdx.x * 256 + threadIdx.x;      // 3*256*2048 total
    int kk  = idx & 2047;
    int rest = idx >> 11;
    int o = rest & 255;
    int l = rest >> 8;
    int i = kk >> 3, f = kk & 7, t = f >> 2, g = f & 3;
    Bt[idx] = (_Float16)fc[(((size_t)(l * 2 + t) * HIDDEN + o) * HIDDEN + i) * GRID_F + g];
}

// Wlt[kk][o], kk = i*5 + d   (fp32 for the kan_line vector GEMM)
__global__ void transpose_line(const float* __restrict__ wl, float* __restrict__ Wlt) {
    int idx = blockIdx.x * 256 + threadIdx.x;      // 320*256
    int o  = idx & 255;
    int kk = idx >> 8;
    int i = kk / 5, d = kk % 5;
    Wlt[idx] = wl[(o * IN_FEAT + i) * 5 + d];
}

// ---------- CSR build (group edges by dst) ----------
__global__ void count_deg(const int* __restrict__ dst, int* __restrict__ counts) {
    int e = blockIdx.x * 256 + threadIdx.x;
    if (e < N_EDGES) atomicAdd(&counts[dst[e]], 1);
}

__global__ void block_sums(const int* __restrict__ counts, int* __restrict__ bsum) {
    int i = blockIdx.x * 256 + threadIdx.x;
    int v = (i < N_NODES) ? counts[i] : 0;
    #pragma unroll
    for (int o = 32; o > 0; o >>= 1) v += __shfl_down(v, o, 64);
    __shared__ int ws[4];
    if ((threadIdx.x & 63) == 0) ws[threadIdx.x >> 6] = v;
    __syncthreads();
    if (threadIdx.x == 0) bsum[blockIdx.x] = ws[0] + ws[1] + ws[2] + ws[3];
}

__global__ void scan_mid(const int* __restrict__ bsum, int* __restrict__ bofs,
                         int* __restrict__ row_start) {
    __shared__ int buf[128];
    int t = threadIdx.x;
    int v = (t < NB_SCAN) ? bsum[t] : 0;
    buf[t] = v;
    __syncthreads();
    for (int d = 1; d < 128; d <<= 1) {
        int x = (t >= d) ? buf[t - d] : 0;
        __syncthreads();
        buf[t] += x;
        __syncthreads();
    }
    if (t < NB_SCAN) bofs[t] = buf[t] - v;          // exclusive
    if (t == NB_SCAN - 1) row_start[N_NODES] = buf[t];
}

__global__ void scan_blocks(const int* __restrict__ counts, const int* __restrict__ bofs,
                            int* __restrict__ row_start) {
    int i = blockIdx.x * 256 + threadIdx.x;
    int val = (i < N_NODES) ? counts[i] : 0;
    int lane = threadIdx.x & 63, wid = threadIdx.x >> 6;
    int v = val;
    #pragma unroll
    for (int d = 1; d < 64; d <<= 1) {
        int t = __shfl_up(v, d, 64);
        if (lane >= d) v += t;
    }
    __shared__ int ws[4];
    if (lane == 63) ws[wid] = v;
    __syncthreads();
    int wofs = 0;
    for (int j = 0; j < wid; ++j) wofs += ws[j];
    if (i < N_NODES) row_start[i] = bofs[blockIdx.x] + wofs + v - val;  // exclusive
}

__global__ void fill_csr(const int* __restrict__ src, const int* __restrict__ dst,
                         const int* __restrict__ row_start, int* __restrict__ cursor,
                         int* __restrict__ ssrc) {
    int e = blockIdx.x * 256 + threadIdx.x;
    if (e < N_EDGES) {
        int d = dst[e];
        int pos = row_start[d] + atomicAdd(&cursor[d], 1);
        ssrc[pos] = src[e];
    }
}

// ---------- aggregation: one wave per node, float4 lanes, unroll-2 ----------
__global__ __launch_bounds__(256)
void aggregate(const float* __restrict__ h, const int* __restrict__ row_start,
               const int* __restrict__ ssrc, float* __restrict__ agg) {
    const int node = blockIdx.x * 4 + (threadIdx.x >> 6);
    const int lane = threadIdx.x & 63;
    const int b = row_start[node], e = row_start[node + 1];
    f32x4 a0 = {0.f, 0.f, 0.f, 0.f}, a1 = {0.f, 0.f, 0.f, 0.f};
    int j = b;
    for (; j + 1 < e; j += 2) {
        int s0 = ssrc[j], s1 = ssrc[j + 1];
        a0 += *(const f32x4*)&h[(size_t)s0 * HIDDEN + lane * 4];
        a1 += *(const f32x4*)&h[(size_t)s1 * HIDDEN + lane * 4];
    }
    if (j < e) {
        int s0 = ssrc[j];
        a0 += *(const f32x4*)&h[(size_t)s0 * HIDDEN + lane * 4];
    }
    *(f32x4*)&agg[(size_t)node * HIDDEN + lane * 4] = a0 + a1;
}

// ---------- kan_line GEMM (fp32 vector ALU; first layer kept high precision) ----------
__global__ __launch_bounds__(256)
void kan_line_gemm(const float* __restrict__ x, const float* __restrict__ Wlt,
                   float* __restrict__ out) {
    __shared__ float At[40 * 32];
    __shared__ float Bs[40 * 256];
    const int tile = blockIdx.x;          // 625 tiles * 32 nodes
    const int tid  = threadIdx.x;
    const int og = tid & 63, mg = tid >> 6;
    const int mA = tid & 31, ilA = tid >> 5;
    float acc[8][4];
    #pragma unroll
    for (int a = 0; a < 8; ++a)
        #pragma unroll
        for (int b = 0; b < 4; ++b) acc[a][b] = 0.f;

    for (int c = 0; c < 8; ++c) {
        int node = tile * 32 + mA;
        float xv = x[(size_t)node * IN_FEAT + c * 8 + ilA];
        float pw = 1.f;
        #pragma unroll
        for (int d = 0; d < 5; ++d) { At[(ilA * 5 + d) * 32 + mA] = pw; pw *= xv; }
        #pragma unroll
        for (int r = 0; r < 40; ++r) Bs[r * 256 + tid] = Wlt[(size_t)(c * 40 + r) * 256 + tid];
        __syncthreads();
        for (int k = 0; k < 40; ++k) {
            float4 a0 = *(const float4*)&At[k * 32 + mg * 8];
            float4 a1 = *(const float4*)&At[k * 32 + mg * 8 + 4];
            float4 bv = *(const float4*)&Bs[k * 256 + og * 4];
            float av[8] = {a0.x, a0.y, a0.z, a0.w, a1.x, a1.y, a1.z, a1.w};
            float bb[4] = {bv.x, bv.y, bv.z, bv.w};
            #pragma unroll
            for (int jm = 0; jm < 8; ++jm)
                #pragma unroll
                for (int j = 0; j < 4; ++j)
                    acc[jm][j] = fmaf(av[jm], bb[j], acc[jm][j]);
        }
        __syncthreads();
    }
    #pragma unroll
    for (int jm = 0; jm < 8; ++jm) {
        int node = tile * 32 + mg * 8 + jm;
        float4 v = make_float4(acc[jm][0], acc[jm][1], acc[jm][2], acc[jm][3]);
        *(float4*)&out[(size_t)node * HIDDEN + og * 4] = v;
    }
}

// ---------- fourier layer via fp16 MFMA, v3 ----------
// BM=32 (626 blocks). Block = 4 waves; wave w: row-tile rt=w&1 (16 rows),
// col-half ch=w>>1 (128 cols = 8 accum tiles). A fragments computed per lane
// in registers (lane (ln,quad) needs exactly agg[row][kc*4+quad]'s 8 features).
// B chunk (256 cols x 32 k fp16 = 16KB) staged global->reg->LDS double-buffered,
// col stride padded to 40 halves (80B) -> bank-balanced b128 reads/writes.
__global__ __launch_bounds__(256)
void fourier_mfma(const float* __restrict__ agg, const float* __restrict__ hold,
                  const _Float16* __restrict__ Bt, float* __restrict__ hnew) {
    __shared__ _Float16 Bs[2][256 * 40];
    const int tid  = threadIdx.x;
    const int w    = tid >> 6;
    const int l    = tid & 63;
    const int ln   = l & 15;
    const int quad = l >> 4;
    const int rt   = w & 1;
    const int ch   = w >> 1;
    const int Mbase = blockIdx.x * 32;
    const int arow  = Mbase + rt * 16 + ln;

    // staging: thread t stages col t's 32-k slice (64B) each chunk
    const _Float16* bcol = Bt + (size_t)tid * KF;

    f32x4 acc[8];
    #pragma unroll
    for (int ct = 0; ct < 8; ++ct) acc[ct] = (f32x4){0.f, 0.f, 0.f, 0.f};

    // prologue: stage chunk 0, prefetch agg chunk 0
    f16x8 st[4];
    #pragma unroll
    for (int j = 0; j < 4; ++j) st[j] = *(const f16x8*)(bcol + j * 8);
    #pragma unroll
    for (int j = 0; j < 4; ++j) *(f16x8*)&Bs[0][tid * 40 + j * 8] = st[j];
    float xv = agg[(size_t)arow * HIDDEN + quad];
    __syncthreads();

    for (int kc = 0; kc < 64; ++kc) {
        const int cur = kc & 1, nxt = cur ^ 1;
        // prefetch next chunk: B (global->reg) and agg scalar
        float xnext = 0.f;
        if (kc < 63) {
            #pragma unroll
            for (int j = 0; j < 4; ++j)
                st[j] = *(const f16x8*)(bcol + (kc + 1) * 32 + j * 8);
            xnext = agg[(size_t)arow * HIDDEN + (kc + 1) * 4 + quad];
        }
        // A fragment from registers: features f = [c1..c4, s1..s4] of xv
        float r = xv * 0.15915494309189535f;
        r -= floorf(r);
        float s1 = __builtin_amdgcn_sinf(r);
        float c1 = __builtin_amdgcn_cosf(r);
        float c2 = c1 * c1 - s1 * s1, s2 = 2.f * s1 * c1;
        float c3 = c2 * c1 - s2 * s1, s3 = s2 * c1 + c2 * s1;
        float c4 = c2 * c2 - s2 * s2, s4 = 2.f * s2 * c2;
        f16x8 af;
        af[0] = (_Float16)c1; af[1] = (_Float16)c2;
        af[2] = (_Float16)c3; af[3] = (_Float16)c4;
        af[4] = (_Float16)s1; af[5] = (_Float16)s2;
        af[6] = (_Float16)s3; af[7] = (_Float16)s4;
        // 8 col-tiles: LDS frag read + MFMA
        #pragma unroll
        for (int ct = 0; ct < 8; ++ct) {
            const int col = ch * 128 + ct * 16 + ln;
            f16x8 bf = *(const f16x8*)&Bs[cur][col * 40 + quad * 8];
            acc[ct] = __builtin_amdgcn_mfma_f32_16x16x32_f16(af, bf, acc[ct], 0, 0, 0);
        }
        // write prefetched B into the other buffer
        if (kc < 63) {
            #pragma unroll
            for (int j = 0; j < 4; ++j) *(f16x8*)&Bs[nxt][tid * 40 + j * 8] = st[j];
        }
        __syncthreads();
        xv = xnext;
    }

    // epilogue: residual + leaky relu (C layout: col=ln, row=quad*4+reg)
    #pragma unroll
    for (int ct = 0; ct < 8; ++ct) {
        const int col = ch * 128 + ct * 16 + ln;
        const int row0 = Mbase + rt * 16 + quad * 4;
        #pragma unroll
        for (int r = 0; r < 4; ++r) {
            const int row = row0 + r;
            if (row < N_NODES) {
                float v = acc[ct][r] + hold[(size_t)row * HIDDEN + col];
                v = v > 0.f ? v : NEG_SLOPE * v;
                hnew[(size_t)row * HIDDEN + col] = v;
            }
        }
    }
}

// ---------- per-graph pooling: gid is SORTED -> segmented register accumulation ----
__global__ void graph_bounds(const int* __restrict__ gid, int* __restrict__ gstart) {
    int g = threadIdx.x;
    if (g < N_GRAPHS) {
        int lo = 0, hi = N_NODES;
        while (lo < hi) { int mid = (lo + hi) >> 1; if (gid[mid] < g) lo = mid + 1; else hi = mid; }
        gstart[g] = lo;
    } else if (g == N_GRAPHS) {
        gstart[g] = N_NODES;
    }
}

__global__ __launch_bounds__(256)
void pool_seg(const float* __restrict__ h, const int* __restrict__ gid,
              float* __restrict__ pooled) {
    const int c = threadIdx.x;
    const int s = blockIdx.x * 128;
    const int e = min(s + 128, N_NODES);
    float acc = 0.f;
    int g = gid[s];
    for (int n = s; n < e; ++n) {
        int gn = gid[n];
        if (gn != g) {
            atomicAdd(&pooled[g * HIDDEN + c], acc);
            acc = 0.f;
            g = gn;
        }
        acc += h[(size_t)n * HIDDEN + c];
    }
    atomicAdd(&pooled[g * HIDDEN + c], acc);
}

// ---------- readout ----------
__global__ void readout(const float* __restrict__ pooled, const int* __restrict__ gstart,
                        const float* __restrict__ wout, const float* __restrict__ bout,
                        float* __restrict__ out) {
    int g = blockIdx.x, t = threadIdx.x;
    float cnt = fmaxf((float)(gstart[g + 1] - gstart[g]), 1.f);
    float y = pooled[g * HIDDEN + t] / cnt;
    float term = wout[t * 2 + 0] + wout[t * 2 + 1] * y;
    #pragma unroll
    for (int o = 32; o > 0; o >>= 1) term += __shfl_down(term, o, 64);
    __shared__ float wsum[4];
    if ((t & 63) == 0) wsum[t >> 6] = term;
    __syncthreads();
    if (t == 0) {
        float s = wsum[0] + wsum[1] + wsum[2] + wsum[3] + bout[0];
        out[g] = 1.f / (1.f + expf(-s));
    }
}

extern "C" void kernel_launch(void* const* d_in, const int* in_sizes, int n_in,
                              void* d_out, int out_size, void* d_ws, size_t ws_size,
                              hipStream_t stream) {
    const float* h_in  = (const float*)d_in[0];
    const int*   src   = (const int*)d_in[1];
    const int*   dst   = (const int*)d_in[2];
    const int*   gid   = (const int*)d_in[3];
    const float* wline = (const float*)d_in[4];
    const float* fcoef = (const float*)d_in[5];
    const float* wout  = (const float*)d_in[6];
    const float* bout  = (const float*)d_in[7];
    float* out = (float*)d_out;

    char* ws = (char*)d_ws;
    size_t off = 0;
    auto alloc = [&](size_t bytes) {
        size_t o = off;
        off += (bytes + 255) & ~size_t(255);
        return o;
    };
    float*     buf0      = (float*)(ws + alloc((size_t)N_PAD * HIDDEN * 4));
    float*     buf1      = (float*)(ws + alloc((size_t)N_PAD * HIDDEN * 4));
    _Float16*  BtF16     = (_Float16*)(ws + alloc((size_t)NLAYERS * KF * HIDDEN * 2));
    float*     Wlt       = (float*)(ws + alloc((size_t)KL * HIDDEN * 4));
    int*       row_start = (int*)(ws + alloc((size_t)(N_NODES + 1) * 4));
    int*       counts    = (int*)(ws + alloc((size_t)N_NODES * 4));
    int*       cursor    = (int*)(ws + alloc((size_t)N_NODES * 4));
    int*       ssrc      = (int*)(ws + alloc((size_t)N_EDGES * 4));
    int*       bsum      = (int*)(ws + alloc((size_t)128 * 4));
    int*       bofs      = (int*)(ws + alloc((size_t)128 * 4));
    int*       gstart    = (int*)(ws + alloc((size_t)(N_GRAPHS + 1) * 4));
    float*     pooled    = (float*)(ws + alloc((size_t)N_GRAPHS * HIDDEN * 4));

    hipMemsetAsync(counts, 0, (size_t)N_NODES * 4, stream);
    hipMemsetAsync(cursor, 0, (size_t)N_NODES * 4, stream);
    hipMemsetAsync(pooled, 0, (size_t)N_GRAPHS * HIDDEN * 4, stream);

    transpose_fourier_f16<<<6144, 256, 0, stream>>>(fcoef, BtF16);
    transpose_line<<<320, 256, 0, stream>>>(wline, Wlt);
    count_deg<<<(N_EDGES + 255) / 256, 256, 0, stream>>>(dst, counts);
    block_sums<<<NB_SCAN, 256, 0, stream>>>(counts, bsum);
    scan_mid<<<1, 128, 0, stream>>>(bsum, bofs, row_start);
    scan_blocks<<<NB_SCAN, 256, 0, stream>>>(counts, bofs, row_start);
    fill_csr<<<(N_EDGES + 255) / 256, 256, 0, stream>>>(src, dst, row_start, cursor, ssrc);
    graph_bounds<<<1, 128, 0, stream>>>(gid, gstart);

    kan_line_gemm<<<625, 256, 0, stream>>>(h_in, Wlt, buf0);

    float* cur = buf0;
    float* other = buf1;
    for (int l = 0; l < NLAYERS; ++l) {
        aggregate<<<N_NODES / 4, 256, 0, stream>>>(cur, row_start, ssrc, other);
        fourier_mfma<<<N_PAD / 32, 256, 0, stream>>>(other, cur,
                                                     BtF16 + (size_t)l * KF * HIDDEN, other);
        float* tmp = cur; cur = other; other = tmp;
    }

    pool_seg<<<(N_NODES + 127) / 128, 256, 0, stream>>>(cur, gid, pooled);
    readout<<<N_GRAPHS, 256, 0, stream>>>(pooled, gstart, wout, bout, out);
}

// Round 5
// 626.032 us; speedup vs baseline: 1.1478x; 1.1478x over previous
//
#include <hip/hip_runtime.h>
#include <math.h>

#define N_NODES   20000
#define N_PAD     20032   // 313 * 64
#define N_EDGES   320000
#define N_GRAPHS  64
#define IN_FEAT   64
#define HIDDEN    256
#define GRID_F    4
#define NLAYERS   3
#define NEG_SLOPE 0.01f

#define KF 2048   // fourier K = HIDDEN * 8 (cos/sin x k=1..4)
#define KL 320    // line K = IN_FEAT * 5 (degrees 0..4)
#define NB_SCAN 79  // ceil(20000/256)

typedef _Float16 f16x8 __attribute__((ext_vector_type(8)));
typedef float    f32x4 __attribute__((ext_vector_type(4)));

// ---------- weight transposes ----------
// fp16 Bt[l][o][kk], kk = i*8 + t*4 + g  (t=0:cos,1:sin ; g -> harmonic k=g+1)
__global__ void transpose_fourier_f16(const float* __restrict__ fc, _Float16* __restrict__ Bt) {
    int idx = blockIdx.x * 256 + threadIdx.x;      // 3*256*2048 total
    int kk  = idx & 2047;
    int rest = idx >> 11;
    int o = rest & 255;
    int l = rest >> 8;
    int i = kk >> 3, f = kk & 7, t = f >> 2, g = f & 3;
    Bt[idx] = (_Float16)fc[(((size_t)(l * 2 + t) * HIDDEN + o) * HIDDEN + i) * GRID_F + g];
}

// Wlt[kk][o], kk = i*5 + d   (fp32 for the kan_line vector GEMM)
__global__ void transpose_line(const float* __restrict__ wl, float* __restrict__ Wlt) {
    int idx = blockIdx.x * 256 + threadIdx.x;      // 320*256
    int o  = idx & 255;
    int kk = idx >> 8;
    int i = kk / 5, d = kk % 5;
    Wlt[idx] = wl[(o * IN_FEAT + i) * 5 + d];
}

// ---------- CSR build (group edges by dst) ----------
__global__ void count_deg(const int* __restrict__ dst, int* __restrict__ counts) {
    int e = blockIdx.x * 256 + threadIdx.x;
    if (e < N_EDGES) atomicAdd(&counts[dst[e]], 1);
}

__global__ void block_sums(const int* __restrict__ counts, int* __restrict__ bsum) {
    int i = blockIdx.x * 256 + threadIdx.x;
    int v = (i < N_NODES) ? counts[i] : 0;
    #pragma unroll
    for (int o = 32; o > 0; o >>= 1) v += __shfl_down(v, o, 64);
    __shared__ int ws[4];
    if ((threadIdx.x & 63) == 0) ws[threadIdx.x >> 6] = v;
    __syncthreads();
    if (threadIdx.x == 0) bsum[blockIdx.x] = ws[0] + ws[1] + ws[2] + ws[3];
}

__global__ void scan_mid(const int* __restrict__ bsum, int* __restrict__ bofs,
                         int* __restrict__ row_start) {
    __shared__ int buf[128];
    int t = threadIdx.x;
    int v = (t < NB_SCAN) ? bsum[t] : 0;
    buf[t] = v;
    __syncthreads();
    for (int d = 1; d < 128; d <<= 1) {
        int x = (t >= d) ? buf[t - d] : 0;
        __syncthreads();
        buf[t] += x;
        __syncthreads();
    }
    if (t < NB_SCAN) bofs[t] = buf[t] - v;          // exclusive
    if (t == NB_SCAN - 1) row_start[N_NODES] = buf[t];
}

__global__ void scan_blocks(const int* __restrict__ counts, const int* __restrict__ bofs,
                            int* __restrict__ row_start) {
    int i = blockIdx.x * 256 + threadIdx.x;
    int val = (i < N_NODES) ? counts[i] : 0;
    int lane = threadIdx.x & 63, wid = threadIdx.x >> 6;
    int v = val;
    #pragma unroll
    for (int d = 1; d < 64; d <<= 1) {
        int t = __shfl_up(v, d, 64);
        if (lane >= d) v += t;
    }
    __shared__ int ws[4];
    if (lane == 63) ws[wid] = v;
    __syncthreads();
    int wofs = 0;
    for (int j = 0; j < wid; ++j) wofs += ws[j];
    if (i < N_NODES) row_start[i] = bofs[blockIdx.x] + wofs + v - val;  // exclusive
}

__global__ void fill_csr(const int* __restrict__ src, const int* __restrict__ dst,
                         const int* __restrict__ row_start, int* __restrict__ cursor,
                         int* __restrict__ ssrc) {
    int e = blockIdx.x * 256 + threadIdx.x;
    if (e < N_EDGES) {
        int d = dst[e];
        int pos = row_start[d] + atomicAdd(&cursor[d], 1);
        ssrc[pos] = src[e];
    }
}

// ---------- aggregation: one wave per node, float4 lanes, unroll-2 ----------
__global__ __launch_bounds__(256)
void aggregate(const float* __restrict__ h, const int* __restrict__ row_start,
               const int* __restrict__ ssrc, float* __restrict__ agg) {
    const int node = blockIdx.x * 4 + (threadIdx.x >> 6);
    const int lane = threadIdx.x & 63;
    const int b = row_start[node], e = row_start[node + 1];
    f32x4 a0 = {0.f, 0.f, 0.f, 0.f}, a1 = {0.f, 0.f, 0.f, 0.f};
    int j = b;
    for (; j + 1 < e; j += 2) {
        int s0 = ssrc[j], s1 = ssrc[j + 1];
        a0 += *(const f32x4*)&h[(size_t)s0 * HIDDEN + lane * 4];
        a1 += *(const f32x4*)&h[(size_t)s1 * HIDDEN + lane * 4];
    }
    if (j < e) {
        int s0 = ssrc[j];
        a0 += *(const f32x4*)&h[(size_t)s0 * HIDDEN + lane * 4];
    }
    *(f32x4*)&agg[(size_t)node * HIDDEN + lane * 4] = a0 + a1;
}

// ---------- kan_line GEMM (fp32 vector ALU; first layer kept high precision) ----------
__global__ __launch_bounds__(256)
void kan_line_gemm(const float* __restrict__ x, const float* __restrict__ Wlt,
                   float* __restrict__ out) {
    __shared__ float At[40 * 32];
    __shared__ float Bs[40 * 256];
    const int tile = blockIdx.x;          // 625 tiles * 32 nodes
    const int tid  = threadIdx.x;
    const int og = tid & 63, mg = tid >> 6;
    const int mA = tid & 31, ilA = tid >> 5;
    float acc[8][4];
    #pragma unroll
    for (int a = 0; a < 8; ++a)
        #pragma unroll
        for (int b = 0; b < 4; ++b) acc[a][b] = 0.f;

    for (int c = 0; c < 8; ++c) {
        int node = tile * 32 + mA;
        float xv = x[(size_t)node * IN_FEAT + c * 8 + ilA];
        float pw = 1.f;
        #pragma unroll
        for (int d = 0; d < 5; ++d) { At[(ilA * 5 + d) * 32 + mA] = pw; pw *= xv; }
        #pragma unroll
        for (int r = 0; r < 40; ++r) Bs[r * 256 + tid] = Wlt[(size_t)(c * 40 + r) * 256 + tid];
        __syncthreads();
        for (int k = 0; k < 40; ++k) {
            float4 a0 = *(const float4*)&At[k * 32 + mg * 8];
            float4 a1 = *(const float4*)&At[k * 32 + mg * 8 + 4];
            float4 bv = *(const float4*)&Bs[k * 256 + og * 4];
            float av[8] = {a0.x, a0.y, a0.z, a0.w, a1.x, a1.y, a1.z, a1.w};
            float bb[4] = {bv.x, bv.y, bv.z, bv.w};
            #pragma unroll
            for (int jm = 0; jm < 8; ++jm)
                #pragma unroll
                for (int j = 0; j < 4; ++j)
                    acc[jm][j] = fmaf(av[jm], bb[j], acc[jm][j]);
        }
        __syncthreads();
    }
    #pragma unroll
    for (int jm = 0; jm < 8; ++jm) {
        int node = tile * 32 + mg * 8 + jm;
        float4 v = make_float4(acc[jm][0], acc[jm][1], acc[jm][2], acc[jm][3]);
        *(float4*)&out[(size_t)node * HIDDEN + og * 4] = v;
    }
}

// ---------- fourier layer via fp16 MFMA, v4: barrier-free single-wave blocks ----------
// 1252 blocks x 64 threads. Wave = 64 rows x 64 cols (4x4 accum tiles).
// No LDS, no __syncthreads. A fragments computed per lane in registers
// (lane (ln,quad), row-tile rt: needs exactly the 8 features of
// agg[Mbase+rt*16+ln][kc*4+quad] -> A[m=ln][k=quad*8+j], verified R2-R4).
// B fragments are contiguous 16B reads from the fp16 [out][k] transpose (L2-hot,
// 313MB/layer total), prefetched one chunk ahead; compiler pipelines via vmcnt.
__global__ __launch_bounds__(64)
void fourier_mfma(const float* __restrict__ agg, const float* __restrict__ hold,
                  const _Float16* __restrict__ Bt, float* __restrict__ hnew) {
    const int l    = threadIdx.x;
    const int ln   = l & 15;
    const int quad = l >> 4;
    const int Mbase = (blockIdx.x >> 2) * 64;
    const int col0  = (blockIdx.x & 3) * 64;

    const _Float16* brow[4];
    #pragma unroll
    for (int ct = 0; ct < 4; ++ct)
        brow[ct] = Bt + (size_t)(col0 + ct * 16 + ln) * KF + quad * 8;

    const float* arow[4];
    #pragma unroll
    for (int rt = 0; rt < 4; ++rt)
        arow[rt] = agg + (size_t)(Mbase + rt * 16 + ln) * HIDDEN + quad;

    f32x4 acc[4][4];
    #pragma unroll
    for (int rt = 0; rt < 4; ++rt)
        #pragma unroll
        for (int ct = 0; ct < 4; ++ct)
            acc[rt][ct] = (f32x4){0.f, 0.f, 0.f, 0.f};

    // prefetch chunk 0
    float xv[4];
    f16x8 bf[4];
    #pragma unroll
    for (int rt = 0; rt < 4; ++rt) xv[rt] = arow[rt][0];
    #pragma unroll
    for (int ct = 0; ct < 4; ++ct) bf[ct] = *(const f16x8*)(brow[ct]);

    for (int kc = 0; kc < 64; ++kc) {
        float xn[4];
        f16x8 bn[4];
        if (kc < 63) {
            #pragma unroll
            for (int ct = 0; ct < 4; ++ct)
                bn[ct] = *(const f16x8*)(brow[ct] + (kc + 1) * 32);
            #pragma unroll
            for (int rt = 0; rt < 4; ++rt)
                xn[rt] = arow[rt][(kc + 1) * 4];
        }
        // A fragments in registers: features [c1..c4, s1..s4] of xv[rt]
        f16x8 af[4];
        #pragma unroll
        for (int rt = 0; rt < 4; ++rt) {
            float r = xv[rt] * 0.15915494309189535f;
            r -= floorf(r);
            float s1 = __builtin_amdgcn_sinf(r);
            float c1 = __builtin_amdgcn_cosf(r);
            float c2 = c1 * c1 - s1 * s1, s2 = 2.f * s1 * c1;
            float c3 = c2 * c1 - s2 * s1, s3 = s2 * c1 + c2 * s1;
            float c4 = c2 * c2 - s2 * s2, s4 = 2.f * s2 * c2;
            f16x8 a;
            a[0] = (_Float16)c1; a[1] = (_Float16)c2;
            a[2] = (_Float16)c3; a[3] = (_Float16)c4;
            a[4] = (_Float16)s1; a[5] = (_Float16)s2;
            a[6] = (_Float16)s3; a[7] = (_Float16)s4;
            af[rt] = a;
        }
        #pragma unroll
        for (int rt = 0; rt < 4; ++rt)
            #pragma unroll
            for (int ct = 0; ct < 4; ++ct)
                acc[rt][ct] = __builtin_amdgcn_mfma_f32_16x16x32_f16(
                    af[rt], bf[ct], acc[rt][ct], 0, 0, 0);
        #pragma unroll
        for (int rt = 0; rt < 4; ++rt) xv[rt] = xn[rt];
        #pragma unroll
        for (int ct = 0; ct < 4; ++ct) bf[ct] = bn[ct];
    }

    // epilogue: residual + leaky relu (C layout: col=ln, row=quad*4+reg)
    #pragma unroll
    for (int rt = 0; rt < 4; ++rt) {
        const int row0 = Mbase + rt * 16 + quad * 4;
        #pragma unroll
        for (int ct = 0; ct < 4; ++ct) {
            const int col = col0 + ct * 16 + ln;
            #pragma unroll
            for (int r = 0; r < 4; ++r) {
                const int row = row0 + r;
                if (row < N_NODES) {
                    float v = acc[rt][ct][r] + hold[(size_t)row * HIDDEN + col];
                    v = v > 0.f ? v : NEG_SLOPE * v;
                    hnew[(size_t)row * HIDDEN + col] = v;
                }
            }
        }
    }
}

// ---------- per-graph pooling: gid is SORTED -> segmented register accumulation ----
__global__ void graph_bounds(const int* __restrict__ gid, int* __restrict__ gstart) {
    int g = threadIdx.x;
    if (g < N_GRAPHS) {
        int lo = 0, hi = N_NODES;
        while (lo < hi) { int mid = (lo + hi) >> 1; if (gid[mid] < g) lo = mid + 1; else hi = mid; }
        gstart[g] = lo;
    } else if (g == N_GRAPHS) {
        gstart[g] = N_NODES;
    }
}

__global__ __launch_bounds__(256)
void pool_seg(const float* __restrict__ h, const int* __restrict__ gid,
              float* __restrict__ pooled) {
    const int c = threadIdx.x;
    const int s = blockIdx.x * 128;
    const int e = min(s + 128, N_NODES);
    float acc = 0.f;
    int g = gid[s];
    for (int n = s; n < e; ++n) {
        int gn = gid[n];
        if (gn != g) {
            atomicAdd(&pooled[g * HIDDEN + c], acc);
            acc = 0.f;
            g = gn;
        }
        acc += h[(size_t)n * HIDDEN + c];
    }
    atomicAdd(&pooled[g * HIDDEN + c], acc);
}

// ---------- readout ----------
__global__ void readout(const float* __restrict__ pooled, const int* __restrict__ gstart,
                        const float* __restrict__ wout, const float* __restrict__ bout,
                        float* __restrict__ out) {
    int g = blockIdx.x, t = threadIdx.x;
    float cnt = fmaxf((float)(gstart[g + 1] - gstart[g]), 1.f);
    float y = pooled[g * HIDDEN + t] / cnt;
    float term = wout[t * 2 + 0] + wout[t * 2 + 1] * y;
    #pragma unroll
    for (int o = 32; o > 0; o >>= 1) term += __shfl_down(term, o, 64);
    __shared__ float wsum[4];
    if ((t & 63) == 0) wsum[t >> 6] = term;
    __syncthreads();
    if (t == 0) {
        float s = wsum[0] + wsum[1] + wsum[2] + wsum[3] + bout[0];
        out[g] = 1.f / (1.f + expf(-s));
    }
}

extern "C" void kernel_launch(void* const* d_in, const int* in_sizes, int n_in,
                              void* d_out, int out_size, void* d_ws, size_t ws_size,
                              hipStream_t stream) {
    const float* h_in  = (const float*)d_in[0];
    const int*   src   = (const int*)d_in[1];
    const int*   dst   = (const int*)d_in[2];
    const int*   gid   = (const int*)d_in[3];
    const float* wline = (const float*)d_in[4];
    const float* fcoef = (const float*)d_in[5];
    const float* wout  = (const float*)d_in[6];
    const float* bout  = (const float*)d_in[7];
    float* out = (float*)d_out;

    char* ws = (char*)d_ws;
    size_t off = 0;
    auto alloc = [&](size_t bytes) {
        size_t o = off;
        off += (bytes + 255) & ~size_t(255);
        return o;
    };
    float*     buf0      = (float*)(ws + alloc((size_t)N_PAD * HIDDEN * 4));
    float*     buf1      = (float*)(ws + alloc((size_t)N_PAD * HIDDEN * 4));
    _Float16*  BtF16     = (_Float16*)(ws + alloc((size_t)NLAYERS * KF * HIDDEN * 2));
    float*     Wlt       = (float*)(ws + alloc((size_t)KL * HIDDEN * 4));
    int*       row_start = (int*)(ws + alloc((size_t)(N_NODES + 1) * 4));
    int*       counts    = (int*)(ws + alloc((size_t)N_NODES * 4));
    int*       cursor    = (int*)(ws + alloc((size_t)N_NODES * 4));
    int*       ssrc      = (int*)(ws + alloc((size_t)N_EDGES * 4));
    int*       bsum      = (int*)(ws + alloc((size_t)128 * 4));
    int*       bofs      = (int*)(ws + alloc((size_t)128 * 4));
    int*       gstart    = (int*)(ws + alloc((size_t)(N_GRAPHS + 1) * 4));
    float*     pooled    = (float*)(ws + alloc((size_t)N_GRAPHS * HIDDEN * 4));

    hipMemsetAsync(counts, 0, (size_t)N_NODES * 4, stream);
    hipMemsetAsync(cursor, 0, (size_t)N_NODES * 4, stream);
    hipMemsetAsync(pooled, 0, (size_t)N_GRAPHS * HIDDEN * 4, stream);

    transpose_fourier_f16<<<6144, 256, 0, stream>>>(fcoef, BtF16);
    transpose_line<<<320, 256, 0, stream>>>(wline, Wlt);
    count_deg<<<(N_EDGES + 255) / 256, 256, 0, stream>>>(dst, counts);
    block_sums<<<NB_SCAN, 256, 0, stream>>>(counts, bsum);
    scan_mid<<<1, 128, 0, stream>>>(bsum, bofs, row_start);
    scan_blocks<<<NB_SCAN, 256, 0, stream>>>(counts, bofs, row_start);
    fill_csr<<<(N_EDGES + 255) / 256, 256, 0, stream>>>(src, dst, row_start, cursor, ssrc);
    graph_bounds<<<1, 128, 0, stream>>>(gid, gstart);

    kan_line_gemm<<<625, 256, 0, stream>>>(h_in, Wlt, buf0);

    float* cur = buf0;
    float* other = buf1;
    for (int l = 0; l < NLAYERS; ++l) {
        aggregate<<<N_NODES / 4, 256, 0, stream>>>(cur, row_start, ssrc, other);
        fourier_mfma<<<(N_PAD / 64) * 4, 64, 0, stream>>>(other, cur,
                                                          BtF16 + (size_t)l * KF * HIDDEN, other);
        float* tmp = cur; cur = other; other = tmp;
    }

    pool_seg<<<(N_NODES + 127) / 128, 256, 0, stream>>>(cur, gid, pooled);
    readout<<<N_GRAPHS, 256, 0, stream>>>(pooled, gstart, wout, bout, out);
}